// Round 1
// baseline (1145.549 us; speedup 1.0000x reference)
//
#include <hip/hip_runtime.h>

#define TT 1024
#define NB 32
#define NJ 128
#define NI 512
#define KD 16

// ---------------- DCLS gaussian kernel construction ----------------
// Kd[d][j][i] = w[i,j] * g[i,j,15-d] / (sum_k g + 1e-7), layout i-contiguous.
__global__ __launch_bounds__(256) void dcls_kern(const float* __restrict__ w,
                                                 const float* __restrict__ P,
                                                 float* __restrict__ Kd) {
    int idx = blockIdx.x * 256 + threadIdx.x;   // idx = j*512 + i  (coalesced Kd writes)
    int i = idx & (NI - 1);
    int j = idx >> 9;
    float wv = w[i * NJ + j];
    float c  = P[i * NJ + j] + (float)(KD / 2);
    float g[KD];
    float s = 0.f;
#pragma unroll
    for (int k = 0; k < KD; ++k) {
        float u = (float)k - c;
        g[k] = expf(-2.0f * u * u);   // exp(-0.5*((k-c)/0.5)^2)
        s += g[k];
    }
    float inv = wv / (s + 1e-7f);
#pragma unroll
    for (int k = 0; k < KD; ++k) {
        int d = (KD - 1) - k;
        Kd[(d * NJ + j) * NI + i] = g[k] * inv;
    }
}

// ---------------- delayed conv: y[t,b,i] = sum_{d,j} Kd[d,j,i] * x[t-d,b,j] ----
// block: 64 t x 128 i for one b. x tile staged in LDS (j-major, t contiguous).
__global__ __launch_bounds__(256) void conv_kern(const float* __restrict__ x,
                                                 const float* __restrict__ Kd,
                                                 float* __restrict__ y) {
    __shared__ float xs[NJ][81];            // 79 t-values, padded to 81 (bank-conflict-free)
    const int t0 = blockIdx.x * 64;
    const int i0 = blockIdx.y * 128;
    const int b  = blockIdx.z;
    const int tid = threadIdx.x;

    // stage x[t0-15 .. t0+63][b][0..127] -> xs[j][tt]
    for (int idx = tid; idx < 79 * NJ; idx += 256) {
        int tt = idx >> 7;
        int j  = idx & (NJ - 1);
        int t  = t0 + tt - 15;
        xs[j][tt] = (t >= 0) ? x[(t * NB + b) * NJ + j] : 0.f;
    }
    __syncthreads();

    const int ithr = tid & 15;              // 16 i-threads * 8 i each
    const int tl   = (tid >> 4) * 4;        // 16 t-threads * 4 t each
    const float* kb = Kd + i0 + ithr * 8;

    float acc[4][8];
#pragma unroll
    for (int r = 0; r < 4; ++r)
#pragma unroll
        for (int c = 0; c < 8; ++c) acc[r][c] = 0.f;

    float4 b0 = *(const float4*)(kb);
    float4 b1 = *(const float4*)(kb + 4);
#pragma unroll 2
    for (int k = 0; k < 2048; ++k) {        // k = d*128 + j
        int kn = (k + 1) & 2047;
        float4 n0 = *(const float4*)(kb + (size_t)kn * NI);
        float4 n1 = *(const float4*)(kb + (size_t)kn * NI + 4);
        int j  = k & (NJ - 1);
        int tb = 15 - (k >> 7) + tl;
        float av[4];
        av[0] = xs[j][tb];
        av[1] = xs[j][tb + 1];
        av[2] = xs[j][tb + 2];
        av[3] = xs[j][tb + 3];
        float bv[8] = {b0.x, b0.y, b0.z, b0.w, b1.x, b1.y, b1.z, b1.w};
#pragma unroll
        for (int r = 0; r < 4; ++r)
#pragma unroll
            for (int c = 0; c < 8; ++c)
                acc[r][c] = fmaf(av[r], bv[c], acc[r][c]);
        b0 = n0;
        b1 = n1;
    }

#pragma unroll
    for (int r = 0; r < 4; ++r) {
        int t = t0 + tl + r;
        float* yp = y + ((size_t)t * NB + b) * NI + i0 + ithr * 8;
        ((float4*)yp)[0] = make_float4(acc[r][0], acc[r][1], acc[r][2], acc[r][3]);
        ((float4*)yp)[1] = make_float4(acc[r][4], acc[r][5], acc[r][6], acc[r][7]);
    }
}

// ---------------- BN stats pass 1: per-block partial sum/sumsq over 128 rows ----
__global__ __launch_bounds__(256) void red1(const float* __restrict__ y,
                                            float* __restrict__ part) {
    int r0 = blockIdx.x * 128;
    int c  = threadIdx.x;
    float s0 = 0.f, q0 = 0.f, s1 = 0.f, q1 = 0.f;
#pragma unroll 4
    for (int r = 0; r < 128; ++r) {
        float v0 = y[(size_t)(r0 + r) * NI + c];
        float v1 = y[(size_t)(r0 + r) * NI + c + 256];
        s0 += v0; q0 = fmaf(v0, v0, q0);
        s1 += v1; q1 = fmaf(v1, v1, q1);
    }
    part[blockIdx.x * NI + c]            = s0;
    part[blockIdx.x * NI + c + 256]      = s1;
    part[256 * NI + blockIdx.x * NI + c]       = q0;
    part[256 * NI + blockIdx.x * NI + c + 256] = q1;
}

// ---------------- BN stats pass 2: combine partials (double), emit scale/bias ----
__global__ __launch_bounds__(512) void red2(const float* __restrict__ part,
                                            const float* __restrict__ gamma,
                                            const float* __restrict__ bbeta,
                                            float* __restrict__ sb) {
    int c = threadIdx.x;   // 512 threads, one block
    double s = 0.0, q = 0.0;
#pragma unroll 8
    for (int p = 0; p < 256; ++p) {
        s += (double)part[p * NI + c];
        q += (double)part[256 * NI + p * NI + c];
    }
    double mean = s / 32768.0;
    double var  = q / 32768.0 - mean * mean;
    double scale = (double)gamma[c] / sqrt(var + 1e-5);
    sb[c]      = (float)scale;
    sb[NI + c] = (float)((double)bbeta[c] - mean * scale);
}

// ---------------- soft-reset LIF scan, in-place over y (=d_out) ----------------
__global__ __launch_bounds__(64) void scan_kern(float* __restrict__ y,
                                                const float* __restrict__ sb,
                                                const float* __restrict__ beta,
                                                const float* __restrict__ U0) {
    int g = blockIdx.x * 64 + threadIdx.x;   // 0..16383 = b*512 + i
    int i = g & (NI - 1);
    float scale = sb[i];
    float bias  = sb[NI + i];
    float bet = beta[i];
    float omb = 1.f - bet;
    float u = U0[g];
    float s = 0.f;
    float* yp = y + g;                       // column stride 16384 floats

    float A[32], Bv[32];
#pragma unroll
    for (int r = 0; r < 32; ++r) A[r] = yp[(size_t)r * 16384];

    for (int t0 = 0; t0 < TT; t0 += 64) {
#pragma unroll
        for (int r = 0; r < 32; ++r) Bv[r] = yp[(size_t)(t0 + 32 + r) * 16384];
#pragma unroll
        for (int r = 0; r < 32; ++r) {
            float z = fmaf(A[r], scale, bias);
            u = fmaf(bet, u - s, omb * z);
            s = (u >= 1.f) ? 1.f : 0.f;
            yp[(size_t)(t0 + r) * 16384] = s;
        }
        if (t0 + 64 < TT) {
#pragma unroll
            for (int r = 0; r < 32; ++r) A[r] = yp[(size_t)(t0 + 64 + r) * 16384];
        }
#pragma unroll
        for (int r = 0; r < 32; ++r) {
            float z = fmaf(Bv[r], scale, bias);
            u = fmaf(bet, u - s, omb * z);
            s = (u >= 1.f) ? 1.f : 0.f;
            yp[(size_t)(t0 + 32 + r) * 16384] = s;
        }
    }
}

extern "C" void kernel_launch(void* const* d_in, const int* in_sizes, int n_in,
                              void* d_out, int out_size, void* d_ws, size_t ws_size,
                              hipStream_t stream) {
    const float* x       = (const float*)d_in[0];
    const float* delay_w = (const float*)d_in[1];
    const float* delay_P = (const float*)d_in[2];
    const float* beta    = (const float*)d_in[3];
    const float* bn_g    = (const float*)d_in[4];
    const float* bn_b    = (const float*)d_in[5];
    const float* U0      = (const float*)d_in[6];
    float* y = (float*)d_out;               // conv result lives in d_out, scan overwrites in place

    float* Kd   = (float*)d_ws;             // 16*128*512 = 1,048,576 floats (4 MiB)
    float* part = Kd + KD * NJ * NI;        // 2*256*512 = 262,144 floats (1 MiB)
    float* sb   = part + 2 * 256 * NI;      // 1024 floats

    dcls_kern<<<dim3(NI * NJ / 256), dim3(256), 0, stream>>>(delay_w, delay_P, Kd);
    conv_kern<<<dim3(TT / 64, NI / 128, NB), dim3(256), 0, stream>>>(x, Kd, y);
    red1<<<dim3(TT * NB / 128), dim3(256), 0, stream>>>(y, part);
    red2<<<dim3(1), dim3(512), 0, stream>>>(part, bn_g, bn_b, sb);
    scan_kern<<<dim3(NB * NI / 64), dim3(64), 0, stream>>>(y, sb, beta, U0);
}

// Round 7
// 413.349 us; speedup vs baseline: 2.7714x; 2.7714x over previous
//
#include <hip/hip_runtime.h>

#define TT 1024
#define NB 32
#define NJ 128
#define NI 512
#define KD 16
#define LDP 40   // padded LDS row length (bf16 elems) = 80B, 16B-aligned, 2-way banks only

typedef short bf16x8 __attribute__((ext_vector_type(8)));   // 8 bf16 (guide-verified operand type)
typedef short bf16x4 __attribute__((ext_vector_type(4)));
typedef float floatx4 __attribute__((ext_vector_type(4)));

struct S3 { short h, m, l; };

// 3-way bf16 truncation split: v = h + m + l + r3, r3 ~ 2^-24 * v. Residuals exact.
__device__ __forceinline__ S3 split3(float v) {
    S3 o;
    unsigned hb = __float_as_uint(v) & 0xFFFF0000u;
    float hf = __uint_as_float(hb);
    float r1 = v - hf;
    unsigned mb = __float_as_uint(r1) & 0xFFFF0000u;
    float mf = __uint_as_float(mb);
    float r2 = r1 - mf;
    unsigned lb = __float_as_uint(r2) & 0xFFFF0000u;
    o.h = (short)(hb >> 16);
    o.m = (short)(mb >> 16);
    o.l = (short)(lb >> 16);
    return o;
}

// ---------------- DCLS gaussian kernel construction ----------------
// Wt[i][k] fp32, k = d*128 + j: Wt[i*2048 + d*128 + j] = w[i,j]*g[i,j,KD-1-d]/(sum g + 1e-7)
__global__ __launch_bounds__(256) void dcls_kern(const float* __restrict__ w,
                                                 const float* __restrict__ P,
                                                 float* __restrict__ Wt) {
    int idx = blockIdx.x * 256 + threadIdx.x;   // idx = i*128 + j
    int j = idx & (NJ - 1);
    int i = idx >> 7;
    float wv = w[i * NJ + j];
    float c  = P[i * NJ + j] + (float)(KD / 2);
    float g[KD];
    float s = 0.f;
#pragma unroll
    for (int k = 0; k < KD; ++k) {
        float u = (float)k - c;
        g[k] = expf(-2.0f * u * u);
        s += g[k];
    }
    float inv = wv / (s + 1e-7f);
#pragma unroll
    for (int k = 0; k < KD; ++k) {
        int d = (KD - 1) - k;                    // conv flip
        Wt[(size_t)i * 2048 + d * NJ + j] = g[k] * inv;
    }
}

// ---------------- MFMA conv: y[t,b,i] = sum_{d,j} Wt[i][d*128+j] * x[t-d,b,j] ----
// 128(t) x 128(i) tile per block, one b. 256 threads = 4 waves (2x2 of 64x64).
// BK=32 (quarter of one d per K-step, 64 steps). 3-way bf16 split, 6 MFMA products.
__global__ __launch_bounds__(256) void conv_mfma(const float* __restrict__ x,
                                                 const float* __restrict__ Wt,
                                                 float* __restrict__ y) {
    __shared__ short Ah[128][LDP];
    __shared__ short Am[128][LDP];
    __shared__ short Al[128][LDP];
    __shared__ short Wh[128][LDP];
    __shared__ short Wm[128][LDP];
    __shared__ short Wl[128][LDP];

    const int t0 = blockIdx.x * 128;
    const int i0 = blockIdx.y * 128;
    const int b  = blockIdx.z;
    const int tid = threadIdx.x;

    const int lane8 = tid & 7;           // staging: 8 lanes x float4 = 32 cols
    const int rw    = tid >> 3;          // 0..31
    const int l    = tid & 63;
    const int wid  = tid >> 6;           // wave 0..3
    const int lr16 = l & 15;             // frag row/col within 16
    const int kb   = l >> 4;             // 0..3: k-octet
    const int wm   = wid >> 1;           // 0..1 -> 64 t-rows each
    const int wn   = wid & 1;            // 0..1 -> 64 i-cols each

    floatx4 acc[4][4];
#pragma unroll
    for (int mf = 0; mf < 4; ++mf)
#pragma unroll
        for (int nf = 0; nf < 4; ++nf)
#pragma unroll
            for (int e = 0; e < 4; ++e) acc[mf][nf][e] = 0.f;

#pragma unroll 1
    for (int kk = 0; kk < 64; ++kk) {
        const int d   = kk >> 2;
        const int j0c = (kk & 3) << 5;

        // ---- global loads (coalesced float4) ----
        float4 ga[4], gw[4];
#pragma unroll
        for (int s = 0; s < 4; ++s) {
            int r = rw + s * 32;
            int t = t0 + r - d;
            float4 va = make_float4(0.f, 0.f, 0.f, 0.f);
            if (t >= 0) va = *(const float4*)(x + ((size_t)t * NB + b) * NJ + j0c + lane8 * 4);
            ga[s] = va;
            gw[s] = *(const float4*)(Wt + (size_t)(i0 + r) * 2048 + kk * 32 + lane8 * 4);
        }

        __syncthreads();                 // previous tile fully consumed

        // ---- 3-way split, LDS writes ----
#pragma unroll
        for (int s = 0; s < 4; ++s) {
            int r  = rw + s * 32;
            int c4 = lane8 * 4;
            S3 s0 = split3(ga[s].x), s1 = split3(ga[s].y), s2 = split3(ga[s].z), s3 = split3(ga[s].w);
            bf16x4 h4, m4, l4;
            h4[0] = s0.h; m4[0] = s0.m; l4[0] = s0.l;
            h4[1] = s1.h; m4[1] = s1.m; l4[1] = s1.l;
            h4[2] = s2.h; m4[2] = s2.m; l4[2] = s2.l;
            h4[3] = s3.h; m4[3] = s3.m; l4[3] = s3.l;
            *(bf16x4*)&Ah[r][c4] = h4;
            *(bf16x4*)&Am[r][c4] = m4;
            *(bf16x4*)&Al[r][c4] = l4;
            s0 = split3(gw[s].x); s1 = split3(gw[s].y); s2 = split3(gw[s].z); s3 = split3(gw[s].w);
            h4[0] = s0.h; m4[0] = s0.m; l4[0] = s0.l;
            h4[1] = s1.h; m4[1] = s1.m; l4[1] = s1.l;
            h4[2] = s2.h; m4[2] = s2.m; l4[2] = s2.l;
            h4[3] = s3.h; m4[3] = s3.m; l4[3] = s3.l;
            *(bf16x4*)&Wh[r][c4] = h4;
            *(bf16x4*)&Wm[r][c4] = m4;
            *(bf16x4*)&Wl[r][c4] = l4;
        }

        __syncthreads();                 // tile kk ready

        // ---- fragments + MFMA: acc += AhWh + AhWm + AmWh + AmWm + AhWl + AlWh ----
        bf16x8 bh[4], bm[4], bl2[4];
#pragma unroll
        for (int nf = 0; nf < 4; ++nf) {
            int row = wn * 64 + nf * 16 + lr16;
            bh[nf]  = *(const bf16x8*)&Wh[row][kb * 8];
            bm[nf]  = *(const bf16x8*)&Wm[row][kb * 8];
            bl2[nf] = *(const bf16x8*)&Wl[row][kb * 8];
        }
#pragma unroll
        for (int mf = 0; mf < 4; ++mf) {
            int row = wm * 64 + mf * 16 + lr16;
            bf16x8 ah = *(const bf16x8*)&Ah[row][kb * 8];
            bf16x8 am = *(const bf16x8*)&Am[row][kb * 8];
            bf16x8 al = *(const bf16x8*)&Al[row][kb * 8];
#pragma unroll
            for (int nf = 0; nf < 4; ++nf)
                acc[mf][nf] = __builtin_amdgcn_mfma_f32_16x16x32_bf16(ah, bh[nf], acc[mf][nf], 0, 0, 0);
#pragma unroll
            for (int nf = 0; nf < 4; ++nf)
                acc[mf][nf] = __builtin_amdgcn_mfma_f32_16x16x32_bf16(ah, bm[nf], acc[mf][nf], 0, 0, 0);
#pragma unroll
            for (int nf = 0; nf < 4; ++nf)
                acc[mf][nf] = __builtin_amdgcn_mfma_f32_16x16x32_bf16(am, bh[nf], acc[mf][nf], 0, 0, 0);
#pragma unroll
            for (int nf = 0; nf < 4; ++nf)
                acc[mf][nf] = __builtin_amdgcn_mfma_f32_16x16x32_bf16(am, bm[nf], acc[mf][nf], 0, 0, 0);
#pragma unroll
            for (int nf = 0; nf < 4; ++nf)
                acc[mf][nf] = __builtin_amdgcn_mfma_f32_16x16x32_bf16(ah, bl2[nf], acc[mf][nf], 0, 0, 0);
#pragma unroll
            for (int nf = 0; nf < 4; ++nf)
                acc[mf][nf] = __builtin_amdgcn_mfma_f32_16x16x32_bf16(al, bh[nf], acc[mf][nf], 0, 0, 0);
        }
    }

    // ---- epilogue: C/D layout col=lane&15, row=(lane>>4)*4+reg [m89-verified] ----
#pragma unroll
    for (int mf = 0; mf < 4; ++mf)
#pragma unroll
        for (int nf = 0; nf < 4; ++nf) {
            int ic = i0 + wn * 64 + nf * 16 + lr16;
#pragma unroll
            for (int q = 0; q < 4; ++q) {
                int t = t0 + wm * 64 + mf * 16 + kb * 4 + q;
                y[((size_t)t * NB + b) * NI + ic] = acc[mf][nf][q];
            }
        }
}

// ---------------- BN stats pass 1: per-block partial sum/sumsq over 128 rows ----
__global__ __launch_bounds__(256) void red1(const float* __restrict__ y,
                                            float* __restrict__ part) {
    int r0 = blockIdx.x * 128;
    int c  = threadIdx.x;
    float s0 = 0.f, q0 = 0.f, s1 = 0.f, q1 = 0.f;
#pragma unroll 4
    for (int r = 0; r < 128; ++r) {
        float v0 = y[(size_t)(r0 + r) * NI + c];
        float v1 = y[(size_t)(r0 + r) * NI + c + 256];
        s0 += v0; q0 = fmaf(v0, v0, q0);
        s1 += v1; q1 = fmaf(v1, v1, q1);
    }
    part[blockIdx.x * NI + c]            = s0;
    part[blockIdx.x * NI + c + 256]      = s1;
    part[256 * NI + blockIdx.x * NI + c]       = q0;
    part[256 * NI + blockIdx.x * NI + c + 256] = q1;
}

// ---------------- BN stats pass 2: combine partials (double), emit scale/bias ----
__global__ __launch_bounds__(512) void red2(const float* __restrict__ part,
                                            const float* __restrict__ gamma,
                                            const float* __restrict__ bbeta,
                                            float* __restrict__ sb) {
    int c = threadIdx.x;
    double s = 0.0, q = 0.0;
#pragma unroll 8
    for (int p = 0; p < 256; ++p) {
        s += (double)part[p * NI + c];
        q += (double)part[256 * NI + p * NI + c];
    }
    double mean = s / 32768.0;
    double var  = q / 32768.0 - mean * mean;
    double scale = (double)gamma[c] / sqrt(var + 1e-5);
    sb[c]      = (float)scale;
    sb[NI + c] = (float)((double)bbeta[c] - mean * scale);
}

// ---------------- soft-reset LIF scan, in-place over y (=d_out) ----------------
__global__ __launch_bounds__(64) void scan_kern(float* __restrict__ y,
                                                const float* __restrict__ sb,
                                                const float* __restrict__ beta,
                                                const float* __restrict__ U0) {
    int g = blockIdx.x * 64 + threadIdx.x;   // 0..16383 = b*512 + i
    int i = g & (NI - 1);
    float scale = sb[i];
    float bias  = sb[NI + i];
    float bet = beta[i];
    float omb = 1.f - bet;
    float u = U0[g];
    float s = 0.f;
    float* yp = y + g;

    float A[32], Bv[32];
#pragma unroll
    for (int r = 0; r < 32; ++r) A[r] = yp[(size_t)r * 16384];

    for (int t0 = 0; t0 < TT; t0 += 64) {
#pragma unroll
        for (int r = 0; r < 32; ++r) Bv[r] = yp[(size_t)(t0 + 32 + r) * 16384];
#pragma unroll
        for (int r = 0; r < 32; ++r) {
            float z = fmaf(A[r], scale, bias);
            u = fmaf(bet, u - s, omb * z);
            s = (u >= 1.f) ? 1.f : 0.f;
            yp[(size_t)(t0 + r) * 16384] = s;
        }
        if (t0 + 64 < TT) {
#pragma unroll
            for (int r = 0; r < 32; ++r) A[r] = yp[(size_t)(t0 + 64 + r) * 16384];
        }
#pragma unroll
        for (int r = 0; r < 32; ++r) {
            float z = fmaf(Bv[r], scale, bias);
            u = fmaf(bet, u - s, omb * z);
            s = (u >= 1.f) ? 1.f : 0.f;
            yp[(size_t)(t0 + 32 + r) * 16384] = s;
        }
    }
}

extern "C" void kernel_launch(void* const* d_in, const int* in_sizes, int n_in,
                              void* d_out, int out_size, void* d_ws, size_t ws_size,
                              hipStream_t stream) {
    const float* x       = (const float*)d_in[0];
    const float* delay_w = (const float*)d_in[1];
    const float* delay_P = (const float*)d_in[2];
    const float* beta    = (const float*)d_in[3];
    const float* bn_g    = (const float*)d_in[4];
    const float* bn_b    = (const float*)d_in[5];
    const float* U0      = (const float*)d_in[6];
    float* y = (float*)d_out;

    float* Wt   = (float*)d_ws;             // 512*2048 fp32 = 4 MiB
    float* part = Wt + (size_t)NI * 2048;   // 2*256*512 = 1 MiB
    float* sb   = part + 2 * 256 * NI;      // 1024 floats

    dcls_kern<<<dim3(NI * NJ / 256), dim3(256), 0, stream>>>(delay_w, delay_P, Wt);
    conv_mfma<<<dim3(TT / 128, NI / 128, NB), dim3(256), 0, stream>>>(x, Wt, y);
    red1<<<dim3(TT * NB / 128), dim3(256), 0, stream>>>(y, part);
    red2<<<dim3(1), dim3(512), 0, stream>>>(part, bn_g, bn_b, sb);
    scan_kern<<<dim3(NB * NI / 64), dim3(64), 0, stream>>>(y, sb, beta, U0);
}